// Round 11
// baseline (118.883 us; speedup 1.0000x reference)
//
#include <hip/hip_runtime.h>
#include <hip/hip_fp16.h>

typedef _Float16 h8 __attribute__((ext_vector_type(8)));
typedef _Float16 h2v __attribute__((ext_vector_type(2)));
typedef __fp16 fp16x2 __attribute__((ext_vector_type(2)));
typedef float f32x4 __attribute__((ext_vector_type(4)));

#define HW 3136    // 56*56
#define NPX 12544  // B*HW
#define YSTR 96    // ytb row stride: 64 y + [1, 0..0] b2 lane
#define XROW 14    // xsb row stride (u32)
#define XSEG 148   // xsb segment stride (u32): >=10*14; 2*148%32==8 -> phase-D x reads
                   //   are a per-half-wave bank permutation (free)
#define PS2 456    // wgt pixel stride (u16): 448 slots + 8 pad; 912B, 16B-aligned
#define WGT_W 3648 // wgt region words: 16 px * 228 (one pixel-half at a time)
// kmain LDS: 3648*4 + 16*148*4 = 24064 B -> 6 blocks/CU (24 waves)

union UH { unsigned int u; h2v h; fp16x2 p; };
__device__ __forceinline__ h2v uh(unsigned int u) { UH v; v.u = u; return v.h; }
__device__ __forceinline__ unsigned int hu(h2v h) { UH v; v.h = h; return v.u; }
#define BLO(w) __builtin_shufflevector(w, w, 0, 0)
#define BHI(w) __builtin_shufflevector(w, w, 1, 1)

__device__ __forceinline__ unsigned int pkrtz(float a, float b) {
    UH v; v.p = __builtin_amdgcn_cvt_pkrtz(a, b); return v.u;
}
__device__ __forceinline__ unsigned short f2hu(float f) {
    union { __half h; unsigned short u; } v; v.h = __float2half(f); return v.u;
}
__device__ __forceinline__ float fget(const float4& v, int e) {
    return e == 0 ? v.x : e == 1 ? v.y : e == 2 ? v.z : v.w;
}

// Merged prep + y-GEMM (all f16).
// blocks 0..391: y = relu(bn(w1 @ x)) for 32 px each -> ytb[px][96]
//   (32-px tile: 2.4 blocks/CU total -> 3x the TLP of the 64-px version;
//    w1 conversion amortized over 2 sub-tiles, w1 is L2-resident anyway)
// blocks 392..615: w2b96[row'][96] = f16([w2 | b2 | 0..]) slot-permuted:
//   row' = c8*448 + g*56 + ki*8 + kj (kj==7 rows zeroed) <-> w2 row (c8*8+g)*49 + ki*7 + kj
__global__ __launch_bounds__(256) void kyw(
    const float* __restrict__ x, const float* __restrict__ w1,
    const float* __restrict__ b1, const float* __restrict__ gamma,
    const float* __restrict__ beta, const float* __restrict__ mean,
    const float* __restrict__ var, const float* __restrict__ w2,
    const float* __restrict__ b2, unsigned short* __restrict__ ytb,
    unsigned short* __restrict__ w2b96)
{
    __shared__ unsigned short xt[32 * 264];    // [px][ch], stride 264 (u32 view: 132)
    const int t = threadIdx.x, bid = blockIdx.x;

    if (bid >= 392) {                          // w2 -> f16 K=96 rows, permuted
        const int r0 = (bid - 392) * 16;
#pragma unroll
        for (int i = 0; i < 6; ++i) {
            int j = i * 256 + t;               // 1536 = 16 rows * 96
            int row = r0 + j / 96, col = j - (j / 96) * 96;
            int c8 = row / 448, rem = row - c8 * 448;
            int g = rem / 56, s = rem - g * 56;
            int ki = s >> 3, kj = s & 7;
            float v = 0.f;
            if (kj < 7) {
                int o = (c8 * 8 + g) * 49 + ki * 7 + kj;
                v = col < 64 ? w2[o * 64 + col] : (col == 64 ? b2[o] : 0.f);
            }
            w2b96[row * 96 + col] = f2hu(v);
        }
        return;
    }

    const int px0 = bid * 32;
    const int b = px0 / HW;
    const int p0 = px0 - b * HW;               // multiple of 32 (3136 % 32 == 0)

    // stage x tile: 256 ch x 32 px fp32 -> f16 xt[px][ch], channel-PAIR packed.
    {
        unsigned int* xw = (unsigned int*)xt;
#pragma unroll
        for (int s = 0; s < 2; ++s)
#pragma unroll
            for (int i = 0; i < 2; ++i) {
                int j = i * 256 + t;           // 512 jobs: (cpair, pixel-quad)
                int cp2 = j >> 2, pq = j & 3;
                const float* s0 = x + (size_t)(b * 256 + cp2 * 2) * HW
                                    + p0 + s * 16 + pq * 4;
                float4 v0 = *(const float4*)(s0);
                float4 v1 = *(const float4*)(s0 + HW);
                int pxb = s * 16 + pq * 4;
                xw[(pxb + 0) * 132 + cp2] = pkrtz(v0.x, v1.x);
                xw[(pxb + 1) * 132 + cp2] = pkrtz(v0.y, v1.y);
                xw[(pxb + 2) * 132 + cp2] = pkrtz(v0.z, v1.z);
                xw[(pxb + 3) * 132 + cp2] = pkrtz(v0.w, v1.w);
            }
    }
    // constant tail of ytb rows: [64]=1.0h (bias lane), [65..95]=0
    if (t < 32) {
        unsigned short* yr = ytb + (size_t)(px0 + t) * YSTR + 64;
        ushort4 one; one.x = 0x3C00u; one.y = 0; one.z = 0; one.w = 0;
        ushort4 z; z.x = 0; z.y = 0; z.z = 0; z.w = 0;
        *(ushort4*)(yr) = one;
#pragma unroll
        for (int q = 1; q < 8; ++q) *(ushort4*)(yr + q * 4) = z;
    }
    __syncthreads();

    const int lane = t & 63, wave = t >> 6;
    const int n = lane & 15, quad = lane >> 4;
    const int m0 = wave * 16;

    // w1 -> f16 A-fragments once per block (amortized over 2 px sub-tiles)
    h8 A[8];
#pragma unroll
    for (int k = 0; k < 8; ++k) {
        const float* wrow = w1 + (m0 + n) * 256 + k * 32 + quad * 8;
        float4 wa = *(const float4*)(wrow);
        float4 wb = *(const float4*)(wrow + 4);
        union { uint4 u; h8 h; } Au;
        Au.u.x = pkrtz(wa.x, wa.y);
        Au.u.y = pkrtz(wa.z, wa.w);
        Au.u.z = pkrtz(wb.x, wb.y);
        Au.u.w = pkrtz(wb.z, wb.w);
        A[k] = Au.h;
    }
    float sc[4], sh[4];
#pragma unroll
    for (int r = 0; r < 4; ++r) {
        int m = m0 + quad * 4 + r;
        sc[r] = gamma[m] * rsqrtf(var[m] + 1e-5f);
        sh[r] = beta[m] - mean[m] * sc[r] + b1[m] * sc[r];
    }

#pragma unroll
    for (int s = 0; s < 2; ++s) {
        f32x4 acc = {0.f, 0.f, 0.f, 0.f};
#pragma unroll
        for (int k = 0; k < 8; ++k) {
            h8 bv = *(const h8*)(&xt[(s * 16 + n) * 264 + k * 32 + quad * 8]);
            acc = __builtin_amdgcn_mfma_f32_16x16x32_f16(A[k], bv, acc, 0, 0, 0);
        }
        uint2 pk;
        pk.x = pkrtz(fmaxf(acc[0] * sc[0] + sh[0], 0.f),
                     fmaxf(acc[1] * sc[1] + sh[1], 0.f));
        pk.y = pkrtz(fmaxf(acc[2] * sc[2] + sh[2], 0.f),
                     fmaxf(acc[3] * sc[3] + sh[3], 0.f));
        *(uint2*)(ytb + (size_t)(px0 + s * 16 + n) * YSTR + m0 + quad * 4) = pk;
    }
}

// One (batch, 8-group chunk) per block; 4x8 pixel tile (32 px) but only HALF the
// weights live in LDS at a time (half-B packed in 14 VGPRs) -> LDS 24064 B,
// 6 blocks/CU (24 waves) WITH the 2x load-chain amortization. grid (32, 7, 14).
// [identical to R10: ~41.5 us]
__global__ __launch_bounds__(256, 6) void kmain(
    const float* __restrict__ x, const unsigned short* __restrict__ w2b96,
    const unsigned short* __restrict__ ytb, float* __restrict__ out)
{
    __shared__ __align__(16) unsigned int smem_u[WGT_W + 16 * XSEG];  // 24064 B
    unsigned short* wgt16 = (unsigned short*)smem_u;
    unsigned int* xsb = smem_u + WGT_W;

    const int t = threadIdx.x;
    const int pix = t & 15, sub = t >> 4;
    const int lane = t & 63, wave = t >> 6;
    const int bc = blockIdx.x;
    const int b = bc >> 3, c8 = bc & 7;       // channels c8*32 .. +31 (8 groups)
    const int w0 = blockIdx.y * 8, h0 = blockIdx.z * 4;
    const int ph = pix >> 3, pw = pix & 7;    // 2 rows x 8 cols (within a half)
    const int n = lane & 15, quad = lane >> 4;

    // A: B-fragments from ytb for BOTH pixel halves (rows h0..h0+1, h0+2..h0+3)
    h8 bfa[3], bfb[3];
    {
        const int Pa = b * HW + (h0 + (n >> 3)) * 56 + w0 + (n & 7);
        const unsigned short* ya = ytb + (size_t)Pa * YSTR + quad * 8;
        bfa[0] = *(const h8*)(ya);
        bfa[1] = *(const h8*)(ya + 32);
        bfa[2] = *(const h8*)(ya + 64);
        const unsigned short* yb2 = ya + (size_t)112 * YSTR;  // +2 rows
        bfb[0] = *(const h8*)(yb2);
        bfb[1] = *(const h8*)(yb2 + 32);
        bfb[2] = *(const h8*)(yb2 + 64);
    }

    // B: stage x halo: seg=(g,cp) x 10 rows (h0-3..h0+6); cols w0-3..w0+10.
    if (t < 160) {
        const int seg = t & 15, jr = t >> 4;   // jr 0..9
        const int jg = seg >> 1, jcp = seg & 1;
        const int hh = h0 + jr - 3;
        const bool rowok = (hh >= 0) && (hh < 56);
        const float* src = x + ((size_t)b * 256 + c8 * 32 + jg * 4 + jcp * 2) * HW + hh * 56;
        float4 va[2][4];
#pragma unroll
        for (int q = 0; q < 4; ++q) {
            int col0 = w0 - 4 + q * 4;
            bool ok = rowok && (col0 >= 0) && (col0 <= 52);
#pragma unroll
            for (int ci = 0; ci < 2; ++ci)
                va[ci][q] = ok ? *(const float4*)(src + ci * HW + col0)
                              : make_float4(0.f, 0.f, 0.f, 0.f);
        }
        unsigned int* dst = xsb + seg * XSEG + jr * XROW;
#pragma unroll
        for (int q = 0; q < 4; ++q)
#pragma unroll
            for (int e = 0; e < 4; ++e) {
                int c = q * 4 + e - 1;               // col index w0-3+c
                if (c >= 0 && c < 14)
                    dst[c] = pkrtz(fget(va[0][q], e), fget(va[1][q], e));
            }
    }

    // C: wgen: each tile's 3 A-fragment loads serve BOTH halves (6 MFMAs).
    //    Half-A -> LDS now; half-B packed into pkb[7] (14 VGPRs), written later.
    uint2 pkb[7];
    {
        const int c0 = c8 * 448;
#pragma unroll
        for (int j = 0; j < 7; ++j) {
            const int tile = wave + 4 * j;
            const unsigned short* ap = w2b96 + (size_t)(c0 + tile * 16 + n) * 96 + quad * 8;
            h8 af0 = *(const h8*)(ap);
            h8 af1 = *(const h8*)(ap + 32);
            h8 af2 = *(const h8*)(ap + 64);
            f32x4 aca = {0.f, 0.f, 0.f, 0.f};
            aca = __builtin_amdgcn_mfma_f32_16x16x32_f16(af0, bfa[0], aca, 0, 0, 0);
            aca = __builtin_amdgcn_mfma_f32_16x16x32_f16(af1, bfa[1], aca, 0, 0, 0);
            aca = __builtin_amdgcn_mfma_f32_16x16x32_f16(af2, bfa[2], aca, 0, 0, 0);
            f32x4 acb = {0.f, 0.f, 0.f, 0.f};
            acb = __builtin_amdgcn_mfma_f32_16x16x32_f16(af0, bfb[0], acb, 0, 0, 0);
            acb = __builtin_amdgcn_mfma_f32_16x16x32_f16(af1, bfb[1], acb, 0, 0, 0);
            acb = __builtin_amdgcn_mfma_f32_16x16x32_f16(af2, bfb[2], acb, 0, 0, 0);
            uint2 pka;
            pka.x = pkrtz(aca[0], aca[1]);
            pka.y = pkrtz(aca[2], aca[3]);
            pkb[j].x = pkrtz(acb[0], acb[1]);
            pkb[j].y = pkrtz(acb[2], acb[3]);
            *(uint2*)(wgt16 + n * PS2 + tile * 16 + quad * 4) = pka;
        }
    }
    __syncthreads();    // xsb + wgt(half A) ready

    const int g = sub & 7, cp = sub >> 3;
    const unsigned int* xrb = xsb + (g * 2 + cp) * XSEG + pw;
    const unsigned short* wr16 = wgt16 + pix * PS2 + g * 56;

    // D-A: involution for pixel half A (output rows h0+0..h0+1)
    {
        const unsigned int* xr = xrb + ph * XROW;
        h2v acA = {(_Float16)0.f, (_Float16)0.f};
        h2v acB = acA;
#pragma unroll
        for (int ki = 0; ki < 7; ++ki) {
            uint4 wq = *(const uint4*)(wr16 + ki * 8);
            const unsigned int* xrow = xr + ki * XROW;
            unsigned int xv[7];
#pragma unroll
            for (int j = 0; j < 7; ++j) xv[j] = xrow[j];
            h2v w01 = uh(wq.x), w23 = uh(wq.y), w45 = uh(wq.z), w6p = uh(wq.w);
            acA += BLO(w01) * uh(xv[0]);
            acB += BHI(w01) * uh(xv[1]);
            acA += BLO(w23) * uh(xv[2]);
            acB += BHI(w23) * uh(xv[3]);
            acA += BLO(w45) * uh(xv[4]);
            acB += BHI(w45) * uh(xv[5]);
            acA += BLO(w6p) * uh(xv[6]);
        }
        h2v acc2 = acA + acB;
        size_t ob = ((size_t)b * 256 + c8 * 32 + g * 4 + cp * 2) * HW
                  + (h0 + ph) * 56 + w0 + pw;
        out[ob] = (float)acc2[0];
        out[ob + HW] = (float)acc2[1];
    }
    __syncthreads();    // all reads of wgt(half A) done

    // C2: dump half-B weights from registers into the same wgt region
    {
#pragma unroll
        for (int j = 0; j < 7; ++j) {
            const int tile = wave + 4 * j;
            *(uint2*)(wgt16 + n * PS2 + tile * 16 + quad * 4) = pkb[j];
        }
    }
    __syncthreads();    // wgt(half B) ready

    // D-B: involution for pixel half B (output rows h0+2..h0+3)
    {
        const unsigned int* xr = xrb + (2 + ph) * XROW;
        h2v acA = {(_Float16)0.f, (_Float16)0.f};
        h2v acB = acA;
#pragma unroll
        for (int ki = 0; ki < 7; ++ki) {
            uint4 wq = *(const uint4*)(wr16 + ki * 8);
            const unsigned int* xrow = xr + ki * XROW;
            unsigned int xv[7];
#pragma unroll
            for (int j = 0; j < 7; ++j) xv[j] = xrow[j];
            h2v w01 = uh(wq.x), w23 = uh(wq.y), w45 = uh(wq.z), w6p = uh(wq.w);
            acA += BLO(w01) * uh(xv[0]);
            acB += BHI(w01) * uh(xv[1]);
            acA += BLO(w23) * uh(xv[2]);
            acB += BHI(w23) * uh(xv[3]);
            acA += BLO(w45) * uh(xv[4]);
            acB += BHI(w45) * uh(xv[5]);
            acA += BLO(w6p) * uh(xv[6]);
        }
        h2v acc2 = acA + acB;
        size_t ob = ((size_t)b * 256 + c8 * 32 + g * 4 + cp * 2) * HW
                  + (h0 + 2 + ph) * 56 + w0 + pw;
        out[ob] = (float)acc2[0];
        out[ob + HW] = (float)acc2[1];
    }
}

extern "C" void kernel_launch(void* const* d_in, const int* in_sizes, int n_in,
                              void* d_out, int out_size, void* d_ws, size_t ws_size,
                              hipStream_t stream) {
    const float* x     = (const float*)d_in[0];
    const float* w1    = (const float*)d_in[1];
    const float* b1    = (const float*)d_in[2];
    const float* gamma = (const float*)d_in[3];
    const float* beta  = (const float*)d_in[4];
    const float* mean  = (const float*)d_in[5];
    const float* var   = (const float*)d_in[6];
    const float* w2    = (const float*)d_in[7];
    const float* b2    = (const float*)d_in[8];
    float* out = (float*)d_out;

    unsigned short* ytb   = (unsigned short*)d_ws;         // 12544*96 u16
    unsigned short* w2b96 = ytb + (size_t)NPX * YSTR;      // 3584*96 u16 (permuted rows)
    hipLaunchKernelGGL(kyw, dim3(616), dim3(256), 0, stream,
                       x, w1, b1, gamma, beta, mean, var, w2, b2, ytb, w2b96);
    hipLaunchKernelGGL(kmain, dim3(32, 7, 14), dim3(256), 0, stream,
                       x, w2b96, ytb, out);
}